// Round 3
// baseline (143.304 us; speedup 1.0000x reference)
//
#include <hip/hip_runtime.h>

#define RING_B (16*6144)                 // 16 row-slots x 6 cols x 1KB = 98304
#define SMEM2  (RING_B + 16*512*4)       // + 16-pixel f32 orow = 131072

typedef __attribute__((ext_vector_type(8))) short bf16x8;
typedef __attribute__((ext_vector_type(4))) float f32x4;
typedef __attribute__((ext_vector_type(4))) unsigned int u32x4;

__device__ __forceinline__ short f2bf(float f) {
  union { float f; unsigned u; } v; v.f = f;
  unsigned r = v.u + 0x7FFFu + ((v.u >> 16) & 1u);   // RNE
  return (short)(r >> 16);
}

__device__ __forceinline__ void gld_lds16(const void* g, void* l) {
  __builtin_amdgcn_global_load_lds(
      (__attribute__((address_space(1))) void*)(g),
      (__attribute__((address_space(3))) void*)(l), 16, 0, 0);
}

// ---- Pass 1: permute channels -> grouped bf16, bake (row,col) XOR swizzle ----
// blockIdx: q = sub*256 + (b*16+strip)  => q%8 == conv-consumer's blockIdx%8 (XCD match)
__global__ __launch_bounds__(256) void permute_kernel(
    const float* __restrict__ x, const int* __restrict__ bin,
    unsigned char* __restrict__ xs)
{
  __shared__ unsigned short pos_tab[512];
  __shared__ char stage[4][2][1024];
  const int t = threadIdx.x;
  { int cA = bin[t], cB = bin[t + 256];
    pos_tab[cA] = (unsigned short)t;
    pos_tab[cB] = (unsigned short)(t + 256); }
  __syncthreads();

  const int w = t >> 6, lane = t & 63;
  const int q = blockIdx.x;
  const int i = q & 255, sub = q >> 8;
  const int b = i >> 4, strip = i & 15;
  const int cb = lane * 4;

#pragma unroll 2
  for (int k = 0; k < 8; ++k) {
    const int idx = w * 8 + k;
    const int r  = sub * 8 + (idx >> 2);
    const int gc = strip * 4 + (idx & 3);
    const int p  = (b * 64 + r) * 64 + gc;
    const unsigned swz = ((unsigned)((r & 3) | ((gc & 1) << 2))) << 4;
    const float* src = x + (size_t)p * 512 + cb;
    f32x4 v0 = *(const f32x4*)src;
    f32x4 v1 = *(const f32x4*)(src + 256);
    char* st = stage[w][k & 1];
#pragma unroll
    for (int j = 0; j < 4; ++j)
      *(short*)(st + ((pos_tab[cb + j] * 2u) ^ swz)) = f2bf(v0[j]);
#pragma unroll
    for (int j = 0; j < 4; ++j)
      *(short*)(st + ((pos_tab[256 + cb + j] * 2u) ^ swz)) = f2bf(v1[j]);
    asm volatile("s_waitcnt lgkmcnt(0)");
    u32x4 d = *(const u32x4*)(st + lane * 16);
    *(u32x4*)(xs + (size_t)p * 1024 + lane * 16) = d;
  }
}

// ---- Pass 2: conv, 4x4-pixel patches, 16-slot row ring, 2 raw barriers / 4 rows ----
__global__ __launch_bounds__(1024, 4) void conv_kernel(
    const unsigned char* __restrict__ xs, const float* __restrict__ wts,
    const float* __restrict__ bias, const int* __restrict__ bout,
    float* __restrict__ out)
{
  extern __shared__ char smem[];
  float* orow = (float*)(smem + RING_B);

  const int t = threadIdx.x, lane = t & 63, g = t >> 6;
  const int g4 = lane >> 4, n16 = lane & 15;
  const int bid = blockIdx.x;            // 256 = b*16 + strip
  const int b = bid >> 4, strip = bid & 15;
  const int w0 = strip * 4;
  const int gbase = g * 64 + g4 * 16;

  u32x4 z4 = {0, 0, 0, 0};
  for (int zz = t * 16; zz < RING_B; zz += 16384)
    *(u32x4*)(smem + zz) = z4;           // zeros cover all halos (rows -1/64, cols -1/64)

  // weight fragments: B elem j <-> ci = g4*8+j (same kappa as A)
  bf16x8 wf[9][2];
  {
    const float* Wg = wts + g * 9216;
#pragma unroll
    for (int tap = 0; tap < 9; ++tap)
#pragma unroll
      for (int nt = 0; nt < 2; ++nt) {
        bf16x8 f;
#pragma unroll
        for (int j = 0; j < 8; ++j)
          f[j] = f2bf(Wg[(tap * 32 + g4 * 8 + j) * 32 + nt * 16 + n16]);
        wf[tap][nt] = f;
      }
  }
  // scatter targets, pre-XORed with pixel-row g4 (bank decorrelation)
  const int opos0x = bout[g * 32 + n16] ^ (g4 << 2);
  const int opos1x = bout[g * 32 + 16 + n16] ^ (g4 << 2);

  // flush: wave g flushes patch-pixel fp=g (row fp>>2, col fp&3), 2KB coalesced
  const int c8 = lane * 8;
  const f32x4 b0 = *(const f32x4*)(bias + c8);
  const f32x4 b1 = *(const f32x4*)(bias + c8 + 4);
  const int fp = g, fg4 = g >> 2;
  const int fq0 = fp * 2048 + ((((lane * 2) + 0) ^ fg4) << 4);
  const int fq1 = fp * 2048 + ((((lane * 2) + 1) ^ fg4) << 4);
  const size_t pixbase = (size_t)((b * 64 + (fp >> 2)) * 64 + w0 + (fp & 3)) * 512 + c8;

  // DMA assignment: d = g and g+16 over (row r = d/6, col c = d%6)
  const int r0 = g / 6,        c0 = g - r0 * 6;
  const int r1 = (g + 16) / 6, c1 = (g + 16) - r1 * 6;
  const int gc0 = w0 - 1 + c0, gc1 = w0 - 1 + c1;
  const bool cv0 = (gc0 >= 0 && gc0 <= 63);
  const bool cv1 = (gc1 >= 0 && gc1 <= 63);
  const unsigned char* xb = xs + (size_t)(b * 64) * 64 * 1024;

  __syncthreads();                       // zeros visible before DMA
  // prologue: stage rows 0..4 (30 DMAs)
  if (cv0) gld_lds16(xb + (size_t)(r0 * 64 + gc0) * 1024 + lane * 16,
                     smem + r0 * 6144 + c0 * 1024);
  if (g < 14 && cv1) gld_lds16(xb + (size_t)(r1 * 64 + gc1) * 1024 + lane * 16,
                               smem + r1 * 6144 + c1 * 1024);
  asm volatile("s_waitcnt vmcnt(0)\ns_barrier" ::: "memory");

  for (int h = 0; h < 64; h += 4) {
    // prefetch rows h+5..h+8 (slots disjoint from live h-1..h+4; drained at bar B)
    {
      int gr0 = h + 5 + r0;
      if (gr0 <= 63 && cv0)
        gld_lds16(xb + (size_t)(gr0 * 64 + gc0) * 1024 + lane * 16,
                  smem + (gr0 & 15) * 6144 + c0 * 1024);
      int gr1 = h + 5 + r1;
      if (g < 8 && gr1 <= 63 && cv1)
        gld_lds16(xb + (size_t)(gr1 * 64 + gc1) * 1024 + lane * 16,
                  smem + (gr1 & 15) * 6144 + c1 * 1024);
      if (h == 56 && t < 384) *(u32x4*)(smem + t * 16) = z4;  // row 64 -> zero slot 0
    }
    asm volatile("" ::: "memory");       // pin DMA issue before MFMA/stores

    // MFMA: 9 taps, A = one swizzled ds_read_b128 each (pixel m=(n16>>2, n16&3))
    f32x4 a0 = {0, 0, 0, 0}, a1 = {0, 0, 0, 0};
#pragma unroll
    for (int dh = 0; dh < 3; ++dh) {
      int gr = h + (n16 >> 2) + dh - 1;
      int rowbase = (gr & 15) * 6144;
      int rsw = (gr & 3) << 4;
#pragma unroll
      for (int dw = 0; dw < 3; ++dw) {
        int cs = (n16 & 3) + dw;                     // col slot 0..5
        int csw = ((w0 - 1 + cs) & 1) << 6;
        const char* ap = smem + rowbase + cs * 1024 + (gbase ^ rsw ^ csw);
        bf16x8 a = *(const bf16x8*)ap;
        a0 = __builtin_amdgcn_mfma_f32_16x16x32_bf16(a, wf[dh * 3 + dw][0], a0, 0, 0, 0);
        a1 = __builtin_amdgcn_mfma_f32_16x16x32_bf16(a, wf[dh * 3 + dw][1], a1, 0, 0, 0);
      }
    }

    // scatter D into orow: pixel = g4*4+rr, channel-quad XORed by g4
#pragma unroll
    for (int rr = 0; rr < 4; ++rr) {
      float* oh = orow + (g4 * 4 + rr) * 512;
      oh[opos0x] = a0[rr];
      oh[opos1x] = a1[rr];
    }
    asm volatile("s_waitcnt lgkmcnt(0)\ns_barrier" ::: "memory");   // bar A

    // flush: bias+relu, 2KB/wave coalesced store (un-XOR channel quads)
    {
      f32x4 y0 = *(const f32x4*)((const char*)orow + fq0);
      f32x4 y1 = *(const f32x4*)((const char*)orow + fq1);
      f32x4 o0, o1;
      o0[0] = fmaxf(y0[0] + b0[0], 0.f); o0[1] = fmaxf(y0[1] + b0[1], 0.f);
      o0[2] = fmaxf(y0[2] + b0[2], 0.f); o0[3] = fmaxf(y0[3] + b0[3], 0.f);
      o1[0] = fmaxf(y1[0] + b1[0], 0.f); o1[1] = fmaxf(y1[1] + b1[1], 0.f);
      o1[2] = fmaxf(y1[2] + b1[2], 0.f); o1[3] = fmaxf(y1[3] + b1[3], 0.f);
      float* dst = out + pixbase + (size_t)h * 32768;
      *(f32x4*)dst = o0;
      *(f32x4*)(dst + 4) = o1;
    }
    // bar B: last 2 VMEM ops are the flush stores -> vmcnt(2) = all DMAs landed,
    // store-acks NOT waited (drain under next iter's MFMA)
    asm volatile("s_waitcnt vmcnt(2) lgkmcnt(0)\ns_barrier" ::: "memory");
  }
}

extern "C" void kernel_launch(void* const* d_in, const int* in_sizes, int n_in,
                              void* d_out, int out_size, void* d_ws, size_t ws_size,
                              hipStream_t stream) {
  const float* x    = (const float*)d_in[0];
  const float* wts  = (const float*)d_in[1];
  const float* bias = (const float*)d_in[2];
  const int*   bin  = (const int*)d_in[3];
  const int*   bout = (const int*)d_in[4];
  float* out = (float*)d_out;
  unsigned char* xs = (unsigned char*)d_ws;   // 64 MiB
  (void)in_sizes; (void)n_in; (void)out_size; (void)ws_size;

  permute_kernel<<<dim3(2048), dim3(256), 0, stream>>>(x, bin, xs);
  conv_kernel<<<dim3(256), dim3(1024), SMEM2, stream>>>(xs, wts, bias, bout, out);
}